// Round 1
// 1224.972 us; speedup vs baseline: 1.0084x; 1.0084x over previous
//
#include <hip/hip_runtime.h>

// CappedMean: out[b,d] = mean(x[b, 0:N[b], d]), x:(B=2048, L=512, D=256) f32.
// Round 3: fused single kernel. Keep 64-row chunks for load balance (caps the
// straggler-block tail at one chunk ~3 us), but each chunk block atomicAdds its
// pre-scaled partial (chunk_sum / N[b]) directly into out, after a 2 MB memset.
// Removes the 16 MB partial-buffer round trip and the latency-bound 64-thread
// final kernel. HBM floor ~537 MB read + 2 MB write (~90 us at 6 TB/s).

constexpr int LL = 512;          // L
constexpr int DD = 256;          // D
constexpr int D4 = DD / 4;       // 64 float4 per row
constexpr int CH = 64;           // rows per chunk
constexpr int NCHUNK = LL / CH;  // 8 chunks per batch

__global__ __launch_bounds__(256) void capped_mean_fused(
    const float* __restrict__ x,
    const int* __restrict__ N,
    float* __restrict__ out) {   // [B, DD], pre-zeroed
  const int b = blockIdx.x;
  const int t = blockIdx.y;
  const int n = N[b];
  const int l0 = t * CH;
  if (l0 >= n) return;  // block-uniform early exit (chunk beyond this batch's length)

  const int lend = (l0 + CH < n) ? (l0 + CH) : n;
  const int tid = threadIdx.x;
  const int d4  = tid & (D4 - 1);  // float4 column 0..63
  const int wl  = tid >> 6;        // wave id 0..3 -> row offset within chunk

  const float4* __restrict__ x4 =
      reinterpret_cast<const float4*>(x + (size_t)b * LL * DD);

  float4 acc = make_float4(0.f, 0.f, 0.f, 0.f);
  // Up to 16 iterations; 64 lanes x 16B coalesced per wave-instruction.
  #pragma unroll 4
  for (int l = l0 + wl; l < lend; l += 4) {
    float4 v = x4[(size_t)l * D4 + d4];
    acc.x += v.x;
    acc.y += v.y;
    acc.z += v.z;
    acc.w += v.w;
  }

  __shared__ float4 red[4][D4];
  red[wl][d4] = acc;
  __syncthreads();

  if (tid < D4) {
    float4 a0 = red[0][tid];
    float4 a1 = red[1][tid];
    float4 a2 = red[2][tid];
    float4 a3 = red[3][tid];
    const float inv = 1.0f / (float)n;
    const float rx = (a0.x + a1.x + a2.x + a3.x) * inv;
    const float ry = (a0.y + a1.y + a2.y + a3.y) * inv;
    const float rz = (a0.z + a1.z + a2.z + a3.z) * inv;
    const float rw = (a0.w + a1.w + a2.w + a3.w) * inv;
    float* o = out + (size_t)b * DD + tid * 4;
    if (n <= CH) {
      // Only chunk 0 is live for this batch: plain coalesced store, no atomics.
      float4 r = make_float4(rx, ry, rz, rw);
      *reinterpret_cast<float4*>(o) = r;
    } else {
      // <= 8 contenders per word (one per live chunk); device-scope by default.
      atomicAdd(o + 0, rx);
      atomicAdd(o + 1, ry);
      atomicAdd(o + 2, rz);
      atomicAdd(o + 3, rw);
    }
  }
}

extern "C" void kernel_launch(void* const* d_in, const int* in_sizes, int n_in,
                              void* d_out, int out_size, void* d_ws, size_t ws_size,
                              hipStream_t stream) {
  const float* x = (const float*)d_in[0];
  const int*   N = (const int*)d_in[1];
  float*     out = (float*)d_out;

  const int B = in_sizes[1];  // 2048

  // out must start at zero: accumulation target for the chunk atomics.
  hipMemsetAsync(out, 0, (size_t)B * DD * sizeof(float), stream);

  dim3 grid(B, NCHUNK);
  hipLaunchKernelGGL(capped_mean_fused, grid, dim3(256), 0, stream, x, N, out);
}